// Round 13
// baseline (12469.477 us; speedup 1.0000x reference)
//
#include <hip/hip_runtime.h>

#define BATCH 128
#define SEQ   1024
#define INSZ  128
#define HID   256
#define NBLK  16
#define NTHR  1024
#define FPB   16           // features per block
#define EPSV  1e-5f
#define WXS   136          // Wx LDS col stride (ushorts): 128+8 -> 16B-aligned rows

typedef __attribute__((ext_vector_type(4))) float f32x4;
typedef __attribute__((ext_vector_type(8))) short short8;
typedef __attribute__((ext_vector_type(4))) unsigned u32x4;   // asm-safe 16B vector
typedef unsigned u32;

__device__ __forceinline__ unsigned short f2bf(float f) {
  unsigned u = __builtin_bit_cast(unsigned, f);
  u += 0x7FFFu + ((u >> 16) & 1u);          // round-to-nearest-even
  return (unsigned short)(u >> 16);
}
// hardware packed f32->bf16 (RNE)
__device__ __forceinline__ short8 xcvt(float4 f0, float4 f1) {
  u32 a, b, c, d2;
  asm("v_cvt_pk_bf16_f32 %0, %1, %2" : "=v"(a)  : "v"(f0.x), "v"(f0.y));
  asm("v_cvt_pk_bf16_f32 %0, %1, %2" : "=v"(b)  : "v"(f0.z), "v"(f0.w));
  asm("v_cvt_pk_bf16_f32 %0, %1, %2" : "=v"(c)  : "v"(f1.x), "v"(f1.y));
  asm("v_cvt_pk_bf16_f32 %0, %1, %2" : "=v"(d2) : "v"(f1.z), "v"(f1.w));
  u32x4 t = {a, b, c, d2};
  return __builtin_bit_cast(short8, t);
}

__launch_bounds__(NTHR)
__global__ void bnlstm_kernel(const float* __restrict__ x,
                              const float* __restrict__ W,
                              const float* __restrict__ gamma,
                              const float* __restrict__ beta,
                              float* __restrict__ out,
                              unsigned short* __restrict__ hbuf,   // [2][16 slab][128 row][16] bf16
                              u32* __restrict__ flags) {           // [16] @128B stride
  // h staging: Zs[32 Kgroup][128 row][8] (K = h features 0..255), conflict profile as R10.
  __shared__ __attribute__((aligned(16))) unsigned short Zs[32 * 1024];    // 64 KB
  __shared__ __attribute__((aligned(16))) unsigned short Wx[64 * WXS];     // x-part W, [col][K]
  __shared__ float red1[2][16][32];                // parity-buffered BN partials
  __shared__ float red2[2][16][32];
  __shared__ float waveTr[16][16][17];             // per-wave gate transpose
  __shared__ __attribute__((aligned(16))) unsigned short hpack[16][16][8];

  const int tid   = threadIdx.x;
  const int bid   = blockIdx.x;
  const int lane  = tid & 63;
  const int wid   = tid >> 6;                      // 16 waves
  const int m     = wid & 7;                       // M-tile: rows m*16..m*16+15
  const int p     = wid >> 3;                      // feature-half: block cols p*32..p*32+31
  const int col16 = lane & 15;
  const int kg    = lane >> 4;
  const int d     = col16 & 3;
  const int q     = col16 >> 2;
  const int arow  = m * 16 + col16;                // A-frag row (batch index)
  const int brow  = m * 16 + kg * 4 + d;           // gate/output row (batch index)

  // ---- Wx (x-part W, K=0..127) -> LDS transposed [64 col][WXS] ----
  {
    const int c = tid >> 4, kb = (tid & 15) * 8;   // c: block-col 0..63
    const int wcol = (c & 3) * HID + bid * FPB + (c >> 2);
    #pragma unroll
    for (int e = 0; e < 8; ++e)
      Wx[c * WXS + kb + e] = f2bf(W[(kb + e) * 1024 + wcol]);
  }

  // ---- wf: h-part W (K=128..383) in regs, 2 col-groups x 8 k-tiles = 64 VGPR ----
  short8 wf[2][8];
  for (int cg2 = 0; cg2 < 2; ++cg2) {
    const int c64 = p * 32 + cg2 * 16 + col16;
    const int wcol = (c64 & 3) * HID + bid * FPB + (c64 >> 2);
    for (int kth = 0; kth < 8; ++kth) {
      short8 v;
      for (int e = 0; e < 8; ++e)
        v[e] = (short)f2bf(W[(128 + kth * 32 + kg * 8 + e) * 1024 + wcol]);
      wf[cg2][kth] = v;
    }
  }
  float gam, bet;
  {
    const int c64 = p * 32 + (lane & 31);
    gam = gamma[(c64 & 3) * HID + bid * FPB + (c64 >> 2)];
    bet = beta [(c64 & 3) * HID + bid * FPB + (c64 >> 2)];
  }
  // bias input skipped: BN subtracts the batch mean, cancelling it exactly.

  __syncthreads();                                 // Wx visible before first use

  float cst[2] = {0.f, 0.f};
  float hnv[2];

  // x loads: issued at the BOTTOM of step t-1, converted at the top of step t
  const float* xbase = x + (size_t)arow * (SEQ * INSZ) + kg * 8;
  float4 xv[8];
  #pragma unroll
  for (int kt = 0; kt < 4; ++kt) {
    xv[2 * kt]     = *(const float4*)(xbase + kt * 32);
    xv[2 * kt + 1] = *(const float4*)(xbase + kt * 32 + 4);
  }

  for (int t = 0; t < SEQ; ++t) {
    const int pR = t & 1;
    f32x4 acc0 = {0.f, 0.f, 0.f, 0.f}, acc1 = {0.f, 0.f, 0.f, 0.f};

    // ---- top: convert + x-part MFMAs (B-frags from Wx LDS; pre-poll, absorbed) ----
    #pragma unroll
    for (int kt = 0; kt < 4; ++kt) {
      short8 ax = xcvt(xv[2 * kt], xv[2 * kt + 1]);
      short8 b0 = *(const short8*)&Wx[(p * 32 + col16) * WXS + kt * 32 + kg * 8];
      short8 b1 = *(const short8*)&Wx[(p * 32 + 16 + col16) * WXS + kt * 32 + kg * 8];
      acc0 = __builtin_amdgcn_mfma_f32_16x16x32_bf16(ax, b0, acc0, 0, 0, 0);
      acc1 = __builtin_amdgcn_mfma_f32_16x16x32_bf16(ax, b1, acc1, 0, 0, 0);
    }

    if (t > 0) {
      // ---- detect: wave 0 polls the 16 spread flag lines ----
      if (wid == 0) {
        const u32 tv = (u32)t;
        while (true) {
          u32 v = (lane < NBLK)
            ? __hip_atomic_load(&flags[lane * 32], __ATOMIC_RELAXED, __HIP_MEMORY_SCOPE_AGENT)
            : tv;
          if (__all((int)(v >= tv))) break;
          __builtin_amdgcn_s_sleep(1);
        }
      }
      __syncthreads();                             // s_a: release

      // ---- stage h: 4 x 16B system-scope loads per thread (65K req/step chip-wide) ----
      const unsigned short* hsrc = hbuf + pR * 32768;
      u32x4 hvv[4];
      #pragma unroll
      for (int k = 0; k < 4; ++k) {
        const unsigned short* ap = hsrc + (tid + k * NTHR) * 8;
        asm volatile("global_load_dwordx4 %0, %1, off sc0 sc1"
                     : "=v"(hvv[k]) : "v"(ap));
      }
      asm volatile("s_waitcnt vmcnt(0)" ::: "memory");
      __builtin_amdgcn_sched_barrier(0);           // rule #18
      #pragma unroll
      for (int k = 0; k < 4; ++k) {
        const int idx = tid + k * NTHR;            // chunk: slab s, row r, half hh
        const int s = idx >> 8, rem = idx & 255, r = rem >> 1, hh = rem & 1;
        *(u32x4*)&Zs[(s * 2 + hh) * 1024 + r * 8] = hvv[k];
      }
      __syncthreads();                             // s1: staging visible

      // ---- h-part MFMAs from LDS ----
      #pragma unroll
      for (int kth = 0; kth < 8; ++kth) {
        short8 af = *(const short8*)&Zs[(kth * 4 + kg) * 1024 + arow * 8];
        acc0 = __builtin_amdgcn_mfma_f32_16x16x32_bf16(af, wf[0][kth], acc0, 0, 0, 0);
        acc1 = __builtin_amdgcn_mfma_f32_16x16x32_bf16(af, wf[1][kth], acc1, 0, 0, 0);
      }
    }

    // ---- BN partials + barrier ----
    {
      float a1 = acc0[0] + acc0[1] + acc0[2] + acc0[3];
      float b1 = acc0[0]*acc0[0] + acc0[1]*acc0[1] + acc0[2]*acc0[2] + acc0[3]*acc0[3];
      float a2 = acc1[0] + acc1[1] + acc1[2] + acc1[3];
      float b2 = acc1[0]*acc1[0] + acc1[1]*acc1[1] + acc1[2]*acc1[2] + acc1[3]*acc1[3];
      a1 += __shfl_xor(a1, 16); b1 += __shfl_xor(b1, 16);
      a1 += __shfl_xor(a1, 32); b1 += __shfl_xor(b1, 32);
      a2 += __shfl_xor(a2, 16); b2 += __shfl_xor(b2, 16);
      a2 += __shfl_xor(a2, 32); b2 += __shfl_xor(b2, 32);
      if (lane < 16) {
        red1[pR][wid][col16] = a1;       red2[pR][wid][col16] = b1;
        red1[pR][wid][16 + col16] = a2;  red2[pR][wid][16 + col16] = b2;
      }
    }
    __syncthreads();                               // s2: partials visible

    // ---- BN finalize: per wave over ITS feature-half (8 same-p waves) ----
    float sc0v, sh0v, sc1v, sh1v;
    {
      const int cidx = lane & 31;
      float S1 = 0.f, S2 = 0.f;
      #pragma unroll
      for (int mm = 0; mm < 8; ++mm) {
        S1 += red1[pR][(p << 3) | mm][cidx];
        S2 += red2[pR][(p << 3) | mm][cidx];
      }
      float mean = S1 * (1.f / BATCH);
      float var  = fmaxf(S2 * (1.f / BATCH) - mean * mean, 0.f);
      float scl = rsqrtf(var + EPSV) * gam;
      float shl = bet - mean * scl;
      sc0v = __shfl(scl, col16);       sh0v = __shfl(shl, col16);
      sc1v = __shfl(scl, 16 + col16);  sh1v = __shfl(shl, 16 + col16);
    }

    // ---- normalize + in-wave transpose + gates; pack h rows ----
    #pragma unroll
    for (int cg2 = 0; cg2 < 2; ++cg2) {
      f32x4 a = cg2 ? acc1 : acc0;
      const float sc = cg2 ? sc1v : sc0v, sh = cg2 ? sh1v : sh0v;
      #pragma unroll
      for (int i = 0; i < 4; ++i)
        waveTr[wid][kg * 4 + i][col16] = a[i] * sc + sh;
      float g0 = waveTr[wid][kg * 4 + d][q * 4 + 0];
      float g1 = waveTr[wid][kg * 4 + d][q * 4 + 1];
      float g2 = waveTr[wid][kg * 4 + d][q * 4 + 2];
      float g3 = waveTr[wid][kg * 4 + d][q * 4 + 3];
      float ig = 1.f / (1.f + __expf(-g0));
      float fg = 1.f / (1.f + __expf(-g1));
      float gg = 1.f - 2.f / (__expf(2.f * g2) + 1.f);
      float og = 1.f / (1.f + __expf(-g3));
      float cn = fg * cst[cg2] + ig * gg;
      float hn = og * (1.f - 2.f / (__expf(2.f * cn) + 1.f));
      cst[cg2] = cn;
      hnv[cg2] = hn;
      hpack[wid][kg * 4 + d][cg2 * 4 + q] = f2bf(hn);
    }

    if (t < SEQ - 1) {
      // ---- publish: one 16B system-scope store per lane<16 per wave ----
      if (lane < 16) {
        u32x4 hv = *(const u32x4*)&hpack[wid][lane][0];
        unsigned short* hd = hbuf + (pR ^ 1) * 32768
                           + bid * 2048 + (m * 16 + lane) * 16 + p * 8;
        asm volatile("global_store_dwordx4 %0, %1, off sc0 sc1"
                     :: "v"(hd), "v"(hv) : "memory");
      }
      asm volatile("s_waitcnt vmcnt(0)" ::: "memory");   // publish acked at MALL
      __syncthreads();                             // s5: all waves proven
      if (tid == 0)
        __hip_atomic_store(&flags[bid * 32], (u32)(t + 1),
                           __ATOMIC_RELAXED, __HIP_MEMORY_SCOPE_AGENT);
      // off-critical-path: out stores + x(t+1) issue
      {
        float* po = &out[(size_t)brow * (SEQ * HID) + (size_t)t * HID + bid * FPB + p * 8];
        po[q]     = hnv[0];
        po[4 + q] = hnv[1];
      }
      const float* xr = xbase + (size_t)(t + 1) * INSZ;
      #pragma unroll
      for (int kt = 0; kt < 4; ++kt) {
        xv[2 * kt]     = *(const float4*)(xr + kt * 32);
        xv[2 * kt + 1] = *(const float4*)(xr + kt * 32 + 4);
      }
    } else {
      float* po = &out[(size_t)brow * (SEQ * HID) + (size_t)t * HID + bid * FPB + p * 8];
      po[q]     = hnv[0];
      po[4 + q] = hnv[1];
      float* ph = &out[(size_t)BATCH * SEQ * HID + (size_t)brow * HID + bid * FPB + p * 8];
      ph[q] = hnv[0];                 ph[4 + q] = hnv[1];                // hy
      ph[BATCH * HID + q] = cst[0];   ph[BATCH * HID + 4 + q] = cst[1];  // cy
    }
  }
}

extern "C" void kernel_launch(void* const* d_in, const int* in_sizes, int n_in,
                              void* d_out, int out_size, void* d_ws, size_t ws_size,
                              hipStream_t stream) {
  const float* x     = (const float*)d_in[0];
  const float* W     = (const float*)d_in[1];
  // d_in[2] = bias: cancelled by BatchNorm, unused.
  const float* gamma = (const float*)d_in[3];
  const float* beta  = (const float*)d_in[4];
  float* out = (float*)d_out;

  u32* flags = (u32*)d_ws;                                         // 16 @128B
  unsigned short* hbuf = (unsigned short*)((char*)d_ws + 4096);    // 2 x 64 KB

  // reset flags each call (t=0 skips the h read, so hbuf needs no init)
  (void)hipMemsetAsync(d_ws, 0, 4096, stream);
  hipLaunchKernelGGL(bnlstm_kernel, dim3(NBLK), dim3(NTHR), 0, stream,
                     x, W, gamma, beta, out, hbuf, flags);
}

// Round 14
// 5278.027 us; speedup vs baseline: 2.3625x; 2.3625x over previous
//
#include <hip/hip_runtime.h>

#define BATCH 128
#define SEQ   1024
#define INSZ  128
#define HID   256
#define NBLK  32
#define NTHR  512
#define FPB   8            // features per block
#define EPSV  1e-5f

typedef __attribute__((ext_vector_type(4))) float f32x4;
typedef __attribute__((ext_vector_type(8))) short short8;
typedef __attribute__((ext_vector_type(4))) unsigned u32x4;   // asm-safe 16B vector
typedef unsigned u32;

__device__ __forceinline__ unsigned short f2bf(float f) {
  unsigned u = __builtin_bit_cast(unsigned, f);
  u += 0x7FFFu + ((u >> 16) & 1u);          // round-to-nearest-even
  return (unsigned short)(u >> 16);
}
// hardware packed f32->bf16 (RNE)
__device__ __forceinline__ short8 xcvt(float4 f0, float4 f1) {
  u32 a, b, c, d2;
  asm("v_cvt_pk_bf16_f32 %0, %1, %2" : "=v"(a)  : "v"(f0.x), "v"(f0.y));
  asm("v_cvt_pk_bf16_f32 %0, %1, %2" : "=v"(b)  : "v"(f0.z), "v"(f0.w));
  asm("v_cvt_pk_bf16_f32 %0, %1, %2" : "=v"(c)  : "v"(f1.x), "v"(f1.y));
  asm("v_cvt_pk_bf16_f32 %0, %1, %2" : "=v"(d2) : "v"(f1.z), "v"(f1.w));
  u32x4 t = {a, b, c, d2};
  return __builtin_bit_cast(short8, t);
}

__launch_bounds__(NTHR)
__global__ void bnlstm_kernel(const float* __restrict__ x,
                              const float* __restrict__ W,
                              const float* __restrict__ gamma,
                              const float* __restrict__ beta,
                              float* __restrict__ out,
                              unsigned short* __restrict__ hbuf,   // [2][32 slab][128 row][8] bf16
                              u32* __restrict__ flags) {           // [32] @128B stride (spread)
  // h staging, col-major by slab (stride 1024 ushorts = R10 layout; the 1032 pad
  // of R12 DOUBLED conflicts -> reverted).
  __shared__ __attribute__((aligned(16))) unsigned short Zs[32 * 1024];     // 64 KB
  __shared__ float red1[2][8][32];                 // parity-buffered BN partials
  __shared__ float red2[2][8][32];
  __shared__ float waveTr[8][16][17];              // per-wave gate transpose
  __shared__ __attribute__((aligned(16))) unsigned short hpack[8][16][8];   // packed h rows

  const int tid   = threadIdx.x;
  const int bid   = blockIdx.x;
  const int lane  = tid & 63;
  const int wid   = tid >> 6;                      // wave w owns batch rows 16w..16w+15
  const int col16 = lane & 15;
  const int kg    = lane >> 4;
  const int d     = col16 & 3;
  const int q     = col16 >> 2;
  const int arow  = wid * 16 + col16;              // A-frag row (batch index)
  const int brow  = wid * 16 + kg * 4 + d;         // gate/output row (batch index)

  // ---- B fragments in registers: 32 cols = (j_local 0..7) x (gate 0..3) ----
  short8 wf[2][12];
  for (int cg = 0; cg < 2; ++cg) {
    const int c32 = cg * 16 + col16;
    const int wcol = (c32 & 3) * HID + bid * FPB + (c32 >> 2);
    for (int kt = 0; kt < 12; ++kt) {
      short8 v;
      for (int e = 0; e < 8; ++e)
        v[e] = (short)f2bf(W[(kt * 32 + kg * 8 + e) * 1024 + wcol]);
      wf[cg][kt] = v;
    }
  }
  float gam = 0.f, bet = 0.f;
  if (lane < 32) {
    gam = gamma[(lane & 3) * HID + bid * FPB + (lane >> 2)];
    bet = beta [(lane & 3) * HID + bid * FPB + (lane >> 2)];
  }
  // bias input skipped: BN subtracts the batch mean, cancelling it exactly.

  float cst[2] = {0.f, 0.f};
  float hnv[2];

  // x(t) f32 loads in flight; converted at the top of step t (static indices only)
  const float* xbase = x + (size_t)arow * (SEQ * INSZ) + kg * 8;
  float4 xv[8];
  #pragma unroll
  for (int kt = 0; kt < 4; ++kt) {
    xv[2 * kt]     = *(const float4*)(xbase + kt * 32);
    xv[2 * kt + 1] = *(const float4*)(xbase + kt * 32 + 4);
  }

  for (int t = 0; t < SEQ; ++t) {
    const int pR = t & 1;
    f32x4 acc0 = {0.f, 0.f, 0.f, 0.f}, acc1 = {0.f, 0.f, 0.f, 0.f};

    // ---- top: convert + x-part MFMAs ----
    #pragma unroll
    for (int kt = 0; kt < 4; ++kt) {
      short8 ax = xcvt(xv[2 * kt], xv[2 * kt + 1]);
      acc0 = __builtin_amdgcn_mfma_f32_16x16x32_bf16(ax, wf[0][kt], acc0, 0, 0, 0);
      acc1 = __builtin_amdgcn_mfma_f32_16x16x32_bf16(ax, wf[1][kt], acc1, 0, 0, 0);
    }
    // ---- immediately reissue x(t+1): drains with the staging vmcnt ----
    if (t + 1 < SEQ) {
      const float* xr = xbase + (size_t)(t + 1) * INSZ;
      #pragma unroll
      for (int kt = 0; kt < 4; ++kt) {
        xv[2 * kt]     = *(const float4*)(xr + kt * 32);
        xv[2 * kt + 1] = *(const float4*)(xr + kt * 32 + 4);
      }
    }

    if (t > 0) {
      // ---- distributed detect+stage: wave w polls ONLY its 4 producers, then
      // ---- stages exactly those slabs. Ready slabs overlap the stragglers. ----
      {
        const u32 tv = (u32)t;
        while (true) {
          u32 v = (lane < 4)
            ? __hip_atomic_load(&flags[(wid * 4 + lane) * 32], __ATOMIC_RELAXED,
                                __HIP_MEMORY_SCOPE_AGENT)
            : tv;
          if (__all((int)(v >= tv))) break;
          __builtin_amdgcn_s_sleep(1);
        }
      }
      const unsigned short* hsrc = hbuf + pR * (BATCH * HID);
      u32x4 hvv[8];
      #pragma unroll
      for (int k = 0; k < 8; ++k) {
        const int slab = wid * 4 + (k >> 1);
        const int row  = (k & 1) * 64 + lane;
        const unsigned short* ap = hsrc + slab * 1024 + row * 8;
        asm volatile("global_load_dwordx4 %0, %1, off sc0 sc1"
                     : "=v"(hvv[k]) : "v"(ap));
      }
      asm volatile("s_waitcnt vmcnt(0)" ::: "memory");
      __builtin_amdgcn_sched_barrier(0);           // rule #18
      #pragma unroll
      for (int k = 0; k < 8; ++k) {
        const int slab = wid * 4 + (k >> 1);
        const int row  = (k & 1) * 64 + lane;
        *(u32x4*)&Zs[slab * 1024 + row * 8] = hvv[k];
      }
      __syncthreads();                             // s1: all slabs staged & visible

      // ---- h-part MFMAs from LDS ----
      #pragma unroll
      for (int kt = 0; kt < 8; ++kt) {
        short8 af = *(const short8*)&Zs[(kt * 4 + kg) * 1024 + arow * 8];
        acc0 = __builtin_amdgcn_mfma_f32_16x16x32_bf16(af, wf[0][4 + kt], acc0, 0, 0, 0);
        acc1 = __builtin_amdgcn_mfma_f32_16x16x32_bf16(af, wf[1][4 + kt], acc1, 0, 0, 0);
      }
    }

    // ---- BN partials + barrier ----
    {
      float a1 = acc0[0] + acc0[1] + acc0[2] + acc0[3];
      float b1 = acc0[0]*acc0[0] + acc0[1]*acc0[1] + acc0[2]*acc0[2] + acc0[3]*acc0[3];
      float a2 = acc1[0] + acc1[1] + acc1[2] + acc1[3];
      float b2 = acc1[0]*acc1[0] + acc1[1]*acc1[1] + acc1[2]*acc1[2] + acc1[3]*acc1[3];
      a1 += __shfl_xor(a1, 16); b1 += __shfl_xor(b1, 16);
      a1 += __shfl_xor(a1, 32); b1 += __shfl_xor(b1, 32);
      a2 += __shfl_xor(a2, 16); b2 += __shfl_xor(b2, 16);
      a2 += __shfl_xor(a2, 32); b2 += __shfl_xor(b2, 32);
      if (lane < 16) {
        red1[pR][wid][lane] = a1;       red2[pR][wid][lane] = b1;
        red1[pR][wid][16 + lane] = a2;  red2[pR][wid][16 + lane] = b2;
      }
    }
    __syncthreads();                               // s2: partials visible

    // ---- BN finalize: redundant per wave (parity-buffered partials) ----
    float sc0v, sh0v, sc1v, sh1v;
    {
      const int cidx = lane & 31;
      float S1 = 0.f, S2 = 0.f;
      #pragma unroll
      for (int w2 = 0; w2 < 8; ++w2) { S1 += red1[pR][w2][cidx]; S2 += red2[pR][w2][cidx]; }
      float mean = S1 * (1.f / BATCH);
      float var  = fmaxf(S2 * (1.f / BATCH) - mean * mean, 0.f);
      float scl = rsqrtf(var + EPSV) * gam;
      float shl = bet - mean * scl;
      sc0v = __shfl(scl, col16);       sh0v = __shfl(shl, col16);
      sc1v = __shfl(scl, 16 + col16);  sh1v = __shfl(shl, 16 + col16);
    }

    // ---- normalize + in-wave transpose + gates; pack h rows ----
    #pragma unroll
    for (int cg = 0; cg < 2; ++cg) {
      f32x4 a = cg ? acc1 : acc0;
      const float sc = cg ? sc1v : sc0v, sh = cg ? sh1v : sh0v;
      #pragma unroll
      for (int i = 0; i < 4; ++i)
        waveTr[wid][kg * 4 + i][col16] = a[i] * sc + sh;
      float g0 = waveTr[wid][kg * 4 + d][q * 4 + 0];
      float g1 = waveTr[wid][kg * 4 + d][q * 4 + 1];
      float g2 = waveTr[wid][kg * 4 + d][q * 4 + 2];
      float g3 = waveTr[wid][kg * 4 + d][q * 4 + 3];
      float ig = 1.f / (1.f + __expf(-g0));
      float fg = 1.f / (1.f + __expf(-g1));
      float gg = 1.f - 2.f / (__expf(2.f * g2) + 1.f);
      float og = 1.f / (1.f + __expf(-g3));
      float cn = fg * cst[cg] + ig * gg;
      float hn = og * (1.f - 2.f / (__expf(2.f * cn) + 1.f));
      cst[cg] = cn;
      hnv[cg] = hn;
      hpack[wid][kg * 4 + d][cg * 4 + q] = f2bf(hn);
    }

    if (t < SEQ - 1) {
      // ---- publish slab rows: ONE 16B system-scope store per lane<16 ----
      if (lane < 16) {
        u32x4 hv = *(const u32x4*)&hpack[wid][lane][0];
        unsigned short* hd = hbuf + (pR ^ 1) * (BATCH * HID)
                           + (bid * 128 + wid * 16 + lane) * 8;
        asm volatile("global_store_dwordx4 %0, %1, off sc0 sc1"
                     :: "v"(hd), "v"(hv) : "memory");
      }
      asm volatile("s_waitcnt vmcnt(0)" ::: "memory");   // publish acked at MALL
      __syncthreads();          // s5: all waves' publishes proven
      if (tid == 0)
        __hip_atomic_store(&flags[bid * 32], (u32)(t + 1),
                           __ATOMIC_RELAXED, __HIP_MEMORY_SCOPE_AGENT);
      // out stores after the flag: off the critical path
      float* po = &out[(size_t)brow * (SEQ * HID) + (size_t)t * HID + bid * FPB];
      po[q]     = hnv[0];
      po[4 + q] = hnv[1];
    } else {
      float* po = &out[(size_t)brow * (SEQ * HID) + (size_t)t * HID + bid * FPB];
      po[q]     = hnv[0];
      po[4 + q] = hnv[1];
      float* ph = &out[(size_t)BATCH * SEQ * HID + (size_t)brow * HID + bid * FPB];
      ph[q] = hnv[0];                 ph[4 + q] = hnv[1];                // hy
      ph[BATCH * HID + q] = cst[0];   ph[BATCH * HID + 4 + q] = cst[1];  // cy
    }
  }
}

extern "C" void kernel_launch(void* const* d_in, const int* in_sizes, int n_in,
                              void* d_out, int out_size, void* d_ws, size_t ws_size,
                              hipStream_t stream) {
  const float* x     = (const float*)d_in[0];
  const float* W     = (const float*)d_in[1];
  // d_in[2] = bias: cancelled by BatchNorm, unused.
  const float* gamma = (const float*)d_in[3];
  const float* beta  = (const float*)d_in[4];
  float* out = (float*)d_out;

  u32* flags = (u32*)d_ws;                                         // 32 @128B = 4 KB
  unsigned short* hbuf = (unsigned short*)((char*)d_ws + 4096);    // 2 x 64 KB

  // reset flags each call (t=0 skips the h read, so hbuf needs no init)
  (void)hipMemsetAsync(d_ws, 0, 4096, stream);
  hipLaunchKernelGGL(bnlstm_kernel, dim3(NBLK), dim3(NTHR), 0, stream,
                     x, W, gamma, beta, out, hbuf, flags);
}

// Round 15
// 4623.474 us; speedup vs baseline: 2.6970x; 1.1416x over previous
//
#include <hip/hip_runtime.h>

#define BATCH 128
#define SEQ   1024
#define INSZ  128
#define HID   256
#define NBLK  32
#define NTHR  512
#define FPB   8            // features per block
#define EPSV  1e-5f

typedef __attribute__((ext_vector_type(4))) float f32x4;
typedef __attribute__((ext_vector_type(8))) short short8;
typedef __attribute__((ext_vector_type(4))) unsigned u32x4;   // asm-safe 16B vector
typedef unsigned u32;

__device__ __forceinline__ unsigned short f2bf(float f) {
  unsigned u = __builtin_bit_cast(unsigned, f);
  u += 0x7FFFu + ((u >> 16) & 1u);          // round-to-nearest-even
  return (unsigned short)(u >> 16);
}
// hardware packed f32->bf16 (RNE)
__device__ __forceinline__ short8 xcvt(float4 f0, float4 f1) {
  u32 a, b, c, d2;
  asm("v_cvt_pk_bf16_f32 %0, %1, %2" : "=v"(a)  : "v"(f0.x), "v"(f0.y));
  asm("v_cvt_pk_bf16_f32 %0, %1, %2" : "=v"(b)  : "v"(f0.z), "v"(f0.w));
  asm("v_cvt_pk_bf16_f32 %0, %1, %2" : "=v"(c)  : "v"(f1.x), "v"(f1.y));
  asm("v_cvt_pk_bf16_f32 %0, %1, %2" : "=v"(d2) : "v"(f1.z), "v"(f1.w));
  u32x4 t = {a, b, c, d2};
  return __builtin_bit_cast(short8, t);
}

__launch_bounds__(NTHR)
__global__ void bnlstm_kernel(const float* __restrict__ x,
                              const float* __restrict__ W,
                              const float* __restrict__ gamma,
                              const float* __restrict__ beta,
                              float* __restrict__ out,
                              unsigned short* __restrict__ hbuf,   // [2][32 slab][128 row][8] bf16
                              u32* __restrict__ flags) {           // [32 blk][8 wave] @128B
  __shared__ __attribute__((aligned(16))) unsigned short Zs[32 * 1024];     // 64 KB
  __shared__ float red1[2][8][32];                 // parity-buffered BN partials
  __shared__ float red2[2][8][32];
  __shared__ float waveTr[8][16][17];              // per-wave gate transpose
  __shared__ __attribute__((aligned(16))) unsigned short hpack[8][16][8];   // packed h rows

  const int tid   = threadIdx.x;
  const int bid   = blockIdx.x;
  const int lane  = tid & 63;
  const int wid   = tid >> 6;                      // wave w owns batch rows 16w..16w+15
  const int col16 = lane & 15;
  const int kg    = lane >> 4;
  const int d     = col16 & 3;
  const int q     = col16 >> 2;
  const int arow  = wid * 16 + col16;              // A-frag row (batch index)
  const int brow  = wid * 16 + kg * 4 + d;         // gate/output row (batch index)

  // ---- B fragments in registers: 32 cols = (j_local 0..7) x (gate 0..3) ----
  short8 wf[2][12];
  for (int cg = 0; cg < 2; ++cg) {
    const int c32 = cg * 16 + col16;
    const int wcol = (c32 & 3) * HID + bid * FPB + (c32 >> 2);
    for (int kt = 0; kt < 12; ++kt) {
      short8 v;
      for (int e = 0; e < 8; ++e)
        v[e] = (short)f2bf(W[(kt * 32 + kg * 8 + e) * 1024 + wcol]);
      wf[cg][kt] = v;
    }
  }
  float gam = 0.f, bet = 0.f;
  if (lane < 32) {
    gam = gamma[(lane & 3) * HID + bid * FPB + (lane >> 2)];
    bet = beta [(lane & 3) * HID + bid * FPB + (lane >> 2)];
  }
  // bias input skipped: BN subtracts the batch mean, cancelling it exactly.

  float cst[2] = {0.f, 0.f};
  float hnv[2];

  // x(t) f32 loads in flight; converted at the top of step t (static indices only)
  const float* xbase = x + (size_t)arow * (SEQ * INSZ) + kg * 8;
  float4 xv[8];
  #pragma unroll
  for (int kt = 0; kt < 4; ++kt) {
    xv[2 * kt]     = *(const float4*)(xbase + kt * 32);
    xv[2 * kt + 1] = *(const float4*)(xbase + kt * 32 + 4);
  }

  for (int t = 0; t < SEQ; ++t) {
    const int pR = t & 1;
    f32x4 acc0 = {0.f, 0.f, 0.f, 0.f}, acc1 = {0.f, 0.f, 0.f, 0.f};

    // ---- top: convert + x-part MFMAs ----
    #pragma unroll
    for (int kt = 0; kt < 4; ++kt) {
      short8 ax = xcvt(xv[2 * kt], xv[2 * kt + 1]);
      acc0 = __builtin_amdgcn_mfma_f32_16x16x32_bf16(ax, wf[0][kt], acc0, 0, 0, 0);
      acc1 = __builtin_amdgcn_mfma_f32_16x16x32_bf16(ax, wf[1][kt], acc1, 0, 0, 0);
    }
    // ---- reissue x(t+1): its latency is absorbed by the poll + stage window ----
    if (t + 1 < SEQ) {
      const float* xr = xbase + (size_t)(t + 1) * INSZ;
      #pragma unroll
      for (int kt = 0; kt < 4; ++kt) {
        xv[2 * kt]     = *(const float4*)(xr + kt * 32);
        xv[2 * kt + 1] = *(const float4*)(xr + kt * 32 + 4);
      }
    }

    if (t > 0) {
      // ---- per-wave detect: wave w polls ONLY the 32 same-w producer flags ----
      {
        const u32 tv = (u32)t;
        while (true) {
          u32 v = (lane < NBLK)
            ? __hip_atomic_load(&flags[(lane * 8 + wid) * 32], __ATOMIC_RELAXED,
                                __HIP_MEMORY_SCOPE_AGENT)
            : tv;
          if (__all((int)(v >= tv))) break;
          __builtin_amdgcn_s_sleep(1);
        }
      }
      // ---- per-wave stage: rows 16w..16w+15 from all 32 slabs (8 x 16B/lane) ----
      const unsigned short* hsrc = hbuf + pR * (BATCH * HID);
      u32x4 hvv[8];
      #pragma unroll
      for (int k = 0; k < 8; ++k) {
        const unsigned short* ap = hsrc + ((k * 4 + kg) * 128 + arow) * 8;
        asm volatile("global_load_dwordx4 %0, %1, off sc0 sc1"
                     : "=v"(hvv[k]) : "v"(ap));
      }
      asm volatile("s_waitcnt vmcnt(0)" ::: "memory");
      __builtin_amdgcn_sched_barrier(0);           // rule #18
      #pragma unroll
      for (int k = 0; k < 8; ++k)
        *(u32x4*)&Zs[((k * 4 + kg) * 128 + arow) * 8] = hvv[k];
      // NO barrier: wave w reads exactly the rows wave w just wrote (lgkmcnt orders)

      // ---- h-part MFMAs from LDS ----
      #pragma unroll
      for (int kt = 0; kt < 8; ++kt) {
        short8 af = *(const short8*)&Zs[((kt * 4 + kg) * 128 + arow) * 8];
        acc0 = __builtin_amdgcn_mfma_f32_16x16x32_bf16(af, wf[0][4 + kt], acc0, 0, 0, 0);
        acc1 = __builtin_amdgcn_mfma_f32_16x16x32_bf16(af, wf[1][4 + kt], acc1, 0, 0, 0);
      }
    }

    // ---- BN partials + the ONE block-wide barrier per step ----
    {
      float a1 = acc0[0] + acc0[1] + acc0[2] + acc0[3];
      float b1 = acc0[0]*acc0[0] + acc0[1]*acc0[1] + acc0[2]*acc0[2] + acc0[3]*acc0[3];
      float a2 = acc1[0] + acc1[1] + acc1[2] + acc1[3];
      float b2 = acc1[0]*acc1[0] + acc1[1]*acc1[1] + acc1[2]*acc1[2] + acc1[3]*acc1[3];
      a1 += __shfl_xor(a1, 16); b1 += __shfl_xor(b1, 16);
      a1 += __shfl_xor(a1, 32); b1 += __shfl_xor(b1, 32);
      a2 += __shfl_xor(a2, 16); b2 += __shfl_xor(b2, 16);
      a2 += __shfl_xor(a2, 32); b2 += __shfl_xor(b2, 32);
      if (lane < 16) {
        red1[pR][wid][lane] = a1;       red2[pR][wid][lane] = b1;
        red1[pR][wid][16 + lane] = a2;  red2[pR][wid][16 + lane] = b2;
      }
    }
    __syncthreads();                               // s2: partials visible (parity-buffered)

    // ---- BN finalize: redundant per wave ----
    float sc0v, sh0v, sc1v, sh1v;
    {
      const int cidx = lane & 31;
      float S1 = 0.f, S2 = 0.f;
      #pragma unroll
      for (int w2 = 0; w2 < 8; ++w2) { S1 += red1[pR][w2][cidx]; S2 += red2[pR][w2][cidx]; }
      float mean = S1 * (1.f / BATCH);
      float var  = fmaxf(S2 * (1.f / BATCH) - mean * mean, 0.f);
      float scl = rsqrtf(var + EPSV) * gam;
      float shl = bet - mean * scl;
      sc0v = __shfl(scl, col16);       sh0v = __shfl(shl, col16);
      sc1v = __shfl(scl, 16 + col16);  sh1v = __shfl(shl, 16 + col16);
    }

    // ---- normalize + in-wave transpose + gates (rcpf: R3-proven accuracy) ----
    #pragma unroll
    for (int cg = 0; cg < 2; ++cg) {
      f32x4 a = cg ? acc1 : acc0;
      const float sc = cg ? sc1v : sc0v, sh = cg ? sh1v : sh0v;
      #pragma unroll
      for (int i = 0; i < 4; ++i)
        waveTr[wid][kg * 4 + i][col16] = a[i] * sc + sh;
      float g0 = waveTr[wid][kg * 4 + d][q * 4 + 0];
      float g1 = waveTr[wid][kg * 4 + d][q * 4 + 1];
      float g2 = waveTr[wid][kg * 4 + d][q * 4 + 2];
      float g3 = waveTr[wid][kg * 4 + d][q * 4 + 3];
      float ig = __builtin_amdgcn_rcpf(1.f + __expf(-g0));
      float fg = __builtin_amdgcn_rcpf(1.f + __expf(-g1));
      float gg = 1.f - 2.f * __builtin_amdgcn_rcpf(__expf(2.f * g2) + 1.f);
      float og = __builtin_amdgcn_rcpf(1.f + __expf(-g3));
      float cn = fg * cst[cg] + ig * gg;
      float hn = og * (1.f - 2.f * __builtin_amdgcn_rcpf(__expf(2.f * cn) + 1.f));
      cst[cg] = cn;
      hnv[cg] = hn;
      hpack[wid][kg * 4 + d][cg * 4 + q] = f2bf(hn);
    }

    if (t < SEQ - 1) {
      // ---- per-wave publish: 16 stores -> OWN vmcnt(0) -> lane0 flag. No barrier. ----
      if (lane < 16) {
        u32x4 hv = *(const u32x4*)&hpack[wid][lane][0];
        unsigned short* hd = hbuf + (pR ^ 1) * (BATCH * HID)
                           + (bid * 128 + wid * 16 + lane) * 8;
        asm volatile("global_store_dwordx4 %0, %1, off sc0 sc1"
                     :: "v"(hd), "v"(hv) : "memory");
      }
      asm volatile("s_waitcnt vmcnt(0)" ::: "memory");   // this wave's stores acked
      if (lane == 0)
        __hip_atomic_store(&flags[(bid * 8 + wid) * 32], (u32)(t + 1),
                           __ATOMIC_RELAXED, __HIP_MEMORY_SCOPE_AGENT);
      // out stores after the flag: off the critical path
      float* po = &out[(size_t)brow * (SEQ * HID) + (size_t)t * HID + bid * FPB];
      po[q]     = hnv[0];
      po[4 + q] = hnv[1];
    } else {
      float* po = &out[(size_t)brow * (SEQ * HID) + (size_t)t * HID + bid * FPB];
      po[q]     = hnv[0];
      po[4 + q] = hnv[1];
      float* ph = &out[(size_t)BATCH * SEQ * HID + (size_t)brow * HID + bid * FPB];
      ph[q] = hnv[0];                 ph[4 + q] = hnv[1];                // hy
      ph[BATCH * HID + q] = cst[0];   ph[BATCH * HID + 4 + q] = cst[1];  // cy
    }
  }
}

extern "C" void kernel_launch(void* const* d_in, const int* in_sizes, int n_in,
                              void* d_out, int out_size, void* d_ws, size_t ws_size,
                              hipStream_t stream) {
  const float* x     = (const float*)d_in[0];
  const float* W     = (const float*)d_in[1];
  // d_in[2] = bias: cancelled by BatchNorm, unused.
  const float* gamma = (const float*)d_in[3];
  const float* beta  = (const float*)d_in[4];
  float* out = (float*)d_out;

  u32* flags = (u32*)d_ws;                                         // 256 @128B = 32 KB
  unsigned short* hbuf = (unsigned short*)((char*)d_ws + 32768);   // 2 x 64 KB

  // reset flags each call (t=0 skips the h read, so hbuf needs no init)
  (void)hipMemsetAsync(d_ws, 0, 32768, stream);
  hipLaunchKernelGGL(bnlstm_kernel, dim3(NBLK), dim3(NTHR), 0, stream,
                     x, W, gamma, beta, out, hbuf, flags);
}